// Round 1
// baseline (323.975 us; speedup 1.0000x reference)
//
#include <hip/hip_runtime.h>
#include <math.h>

#define Bb 8
#define Vv 3
#define Ss 1200
#define Ff 16
#define Hh 32
#define Kk 10
#define STEPS 12
#define ROWS (Bb*Vv*Ss)          // 28800
#define L (Vv*Ss)                // 3600

// ---------------- Kernel A: Wh = feat @ W_gat  (+ f = Wh.a1, g = Wh.a2) ----------------
__global__ __launch_bounds__(256) void gat_wh_k(const float* __restrict__ feat,
                                                const float* __restrict__ W_gat,
                                                const float* __restrict__ a_gat,
                                                float* __restrict__ Wh,
                                                float* __restrict__ fvec,
                                                float* __restrict__ gvec) {
    int blk = blockIdx.x;                 // b*450 + v*150 + c
    int c = blk % 150;
    int v = (blk / 150) % Vv;
    int b = blk / (150 * Vv);
    int tid = threadIdx.x;
    int r = tid >> 5;                     // 0..7 row-in-block
    int h = tid & 31;
    int s = c * 8 + r;

    __shared__ float Wg[16][32];
    __shared__ float fe[8][16];
    for (int i = tid; i < 512; i += 256) Wg[i >> 5][i & 31] = W_gat[v * 512 + i];
    for (int i = tid; i < 128; i += 256) fe[i >> 4][i & 15] = feat[(b * Ss + c * 8) * Ff + i];
    __syncthreads();

    float acc = 0.f;
#pragma unroll
    for (int k = 0; k < 16; ++k) acc += fe[r][k] * Wg[k][h];

    int row = (b * Vv + v) * Ss + s;
    Wh[(size_t)row * Hh + h] = acc;

    float a1 = a_gat[v * 64 + h];
    float a2 = a_gat[v * 64 + 32 + h];
    float pf = acc * a1, pg = acc * a2;
#pragma unroll
    for (int m = 16; m >= 1; m >>= 1) {
        pf += __shfl_xor(pf, m);
        pg += __shfl_xor(pg, m);
    }
    if (h == 0) { fvec[row] = pf; gvec[row] = pg; }
}

// ---------------- Kernel A2: Gmax[b,v] = max_t g[b,v,t] ----------------
__global__ __launch_bounds__(256) void gmax_k(const float* __restrict__ gvec,
                                              float* __restrict__ Gmax) {
    int bv = blockIdx.x;
    int tid = threadIdx.x;
    float m = -3.0e38f;
    for (int t = tid; t < Ss; t += 256) m = fmaxf(m, gvec[bv * Ss + t]);
#pragma unroll
    for (int mm = 32; mm >= 1; mm >>= 1) m = fmaxf(m, __shfl_xor(m, mm));
    __shared__ float red[4];
    if ((tid & 63) == 0) red[tid >> 6] = m;
    __syncthreads();
    if (tid == 0) Gmax[bv] = fmaxf(fmaxf(red[0], red[1]), fmaxf(red[2], red[3]));
}

// ---------------- Kernel B: sparse GAT attention row:  hid = elu(softmax(e)@Wh) ----------------
__global__ __launch_bounds__(64) void gat_attn_k(const float* __restrict__ adj,
                                                 const float* __restrict__ Wh,
                                                 const float* __restrict__ fvec,
                                                 const float* __restrict__ gvec,
                                                 const float* __restrict__ Gmax,
                                                 float* __restrict__ hid) {
    int row = blockIdx.x;                 // (b*3+v)*1200 + s
    int bv = row / Ss;
    int lane = threadIdx.x;
    const float* adj_row = adj + (size_t)row * Ss;
    const float* grow = gvec + (size_t)bv * Ss;
    const float* Whbv = Wh + (size_t)bv * Ss * Hh;
    float fr = fvec[row];
    float M = fr + Gmax[bv];
    M = (M > 0.f) ? M : 0.2f * M;         // leaky_relu of upper bound -> >= true row max

    __shared__ int   ct[64];
    __shared__ float cp[64];

    float acc = 0.f, psum = 0.f;
    int h = lane & 31, jp = lane >> 5;

    // prefetch chunk 0
    float a  = (lane < Ss) ? adj_row[lane] : 0.f;
    float gt = (lane < Ss) ? grow[lane]    : 0.f;

    for (int c = 0; c < 19; ++c) {
        // prefetch next chunk
        float a_n = 0.f, g_n = 0.f;
        int tn = (c + 1) * 64 + lane;
        if (tn < Ss) { a_n = adj_row[tn]; g_n = grow[tn]; }

        int t = c * 64 + lane;
        bool nz = (a > 0.f);
        unsigned long long mask = __ballot(nz);
        if (mask != 0ull) {
            int cnt = __popcll(mask);
            if (nz) {
                float e = fr + gt;
                e = (e > 0.f) ? e : 0.2f * e;
                float p = __expf(e - M);
                psum += p;
                int pos = __popcll(mask & ((1ull << lane) - 1ull));
                ct[pos] = t;
                cp[pos] = p;
            }
            __syncthreads();
            for (int j = jp; j < cnt; j += 2)
                acc += cp[j] * Whbv[(size_t)ct[j] * Hh + h];
            __syncthreads();
        }
        a = a_n; gt = g_n;
    }

#pragma unroll
    for (int mm = 32; mm >= 1; mm >>= 1) psum += __shfl_xor(psum, mm);
    acc += __shfl_xor(acc, 32);
    float r = acc / psum;
    float hv = (r > 0.f) ? r : expm1f(r);
    if (lane < 32) hid[(size_t)row * Hh + h] = hv;
}

// ---------------- Kernel C: qkv = hid @ qkv_W + qkv_b ----------------
__global__ __launch_bounds__(256) void qkv_k(const float* __restrict__ hid,
                                             const float* __restrict__ qkv_W,
                                             const float* __restrict__ qkv_b,
                                             float* __restrict__ qkv) {
    int idx = blockIdx.x * 256 + threadIdx.x;   // < 28800*96
    int row = idx / 96, col = idx % 96;
    const float* x = hid + (size_t)row * Hh;
    float acc = qkv_b[col];
#pragma unroll
    for (int i = 0; i < 32; ++i) acc += x[i] * qkv_W[i * 96 + col];
    qkv[idx] = acc;
}

// ---------------- Kernel D: self-attn (33 rows/batch) + o-proj + fuse + gate ----------------
__global__ __launch_bounds__(256) void attn_k(const float* __restrict__ hid,
                                              const float* __restrict__ qkv,
                                              const float* __restrict__ o_W,
                                              const float* __restrict__ o_b,
                                              const float* __restrict__ fus_W,
                                              const float* __restrict__ fus_b,
                                              float* __restrict__ hfg) {
    int blk = blockIdx.x;                 // b*33 + si*3 + v
    int b = blk / 33;
    int rem = blk % 33;
    int si = rem / 3;
    int v = rem % 3;
    int s = 2 * 400 + si;                 // 800 + si
    int l = v * Ss + s;
    int tid = threadIdx.x;
    const float inv = 0.1767766952966369f; // 1/sqrt(32)

    __shared__ float qv[32];
    __shared__ float pl[L];
    __shared__ float red[4];
    __shared__ float part[8][32];
    __shared__ float sa[32];
    __shared__ float hf[32];

    const float* qrow = qkv + ((size_t)b * L + l) * 96;
    if (tid < 32) qv[tid] = qrow[tid];
    __syncthreads();

    // logits + max
    float lmax = -3.0e38f;
    for (int m = tid; m < L; m += 256) {
        const float* krow = qkv + ((size_t)b * L + m) * 96 + 32;
        float acc = 0.f;
#pragma unroll
        for (int i = 0; i < 32; ++i) acc += qv[i] * krow[i];
        acc *= inv;
        pl[m] = acc;
        lmax = fmaxf(lmax, acc);
    }
#pragma unroll
    for (int mm = 32; mm >= 1; mm >>= 1) lmax = fmaxf(lmax, __shfl_xor(lmax, mm));
    if ((tid & 63) == 0) red[tid >> 6] = lmax;
    __syncthreads();
    lmax = fmaxf(fmaxf(red[0], red[1]), fmaxf(red[2], red[3]));
    __syncthreads();

    // exp + sum
    float lsum = 0.f;
    for (int m = tid; m < L; m += 256) {
        float p = __expf(pl[m] - lmax);
        pl[m] = p;
        lsum += p;
    }
#pragma unroll
    for (int mm = 32; mm >= 1; mm >>= 1) lsum += __shfl_xor(lsum, mm);
    __syncthreads();
    if ((tid & 63) == 0) red[tid >> 6] = lsum;
    __syncthreads();
    lsum = red[0] + red[1] + red[2] + red[3];

    // weighted sum of V
    int h = tid & 31, mg = tid >> 5;
    float acc = 0.f;
    for (int m = mg; m < L; m += 8)
        acc += pl[m] * qkv[((size_t)b * L + m) * 96 + 64 + h];
    part[mg][h] = acc;
    __syncthreads();
    if (tid < 32) {
        float sacc = 0.f;
#pragma unroll
        for (int j = 0; j < 8; ++j) sacc += part[j][tid];
        sa[tid] = sacc / lsum;
    }
    __syncthreads();
    if (tid < 32) {
        float o = o_b[tid];
#pragma unroll
        for (int i = 0; i < 32; ++i) o += sa[i] * o_W[i * 32 + tid];
        float x = hid[((size_t)b * L + l) * Hh + tid];
        hf[tid] = 0.8f * o + 0.2f * x;
    }
    __syncthreads();
    if (tid < 32) {
        float gacc = fus_b[tid];
#pragma unroll
        for (int i = 0; i < 32; ++i) gacc += hf[i] * fus_W[i * 32 + tid];
        float gate = 1.f / (1.f + __expf(-gacc));
        hfg[(size_t)blk * 32 + tid] = gate * hf[tid];
    }
}

// ---------------- Kernel E: scores + softmax + ctx + GRU ----------------
__global__ __launch_bounds__(64) void head_k(const float* __restrict__ hfg,
                                             const float* __restrict__ dis_lab,
                                             const float* __restrict__ att1_W,
                                             const float* __restrict__ att1_b,
                                             const float* __restrict__ att2_W,
                                             const float* __restrict__ att2_b,
                                             const float* __restrict__ Wih,
                                             const float* __restrict__ Whh,
                                             const float* __restrict__ bih,
                                             const float* __restrict__ bhh,
                                             const float* __restrict__ out_W,
                                             const float* __restrict__ out_b,
                                             float* __restrict__ out) {
    int b = blockIdx.x;
    int tid = threadIdx.x;
    __shared__ float lab[11][32];         // rows 0..9 label, 10 unlabel
    __shared__ float sc[10];
    __shared__ float hS[32], xS[32], h2S[32];

    for (int i = tid; i < 352; i += 64) {
        int k = i >> 5, hh = i & 31;
        float val = 0.f;
#pragma unroll
        for (int v = 0; v < 3; ++v) val += hfg[(size_t)(b * 33 + k * 3 + v) * 32 + hh];
        lab[k][hh] = val;
    }
    __syncthreads();

    if (tid < 10) {
        float s_acc = att2_b[0];
        for (int j = 0; j < 32; ++j) {
            float t1 = att1_b[j];
#pragma unroll
            for (int i = 0; i < 32; ++i) t1 += lab[tid][i] * att1_W[i * 32 + j];
#pragma unroll
            for (int i = 0; i < 32; ++i) t1 += lab[10][i] * att1_W[(32 + i) * 32 + j];
            t1 = fmaxf(t1, 0.f);
            s_acc += t1 * att2_W[j];
        }
        sc[tid] = s_acc * dis_lab[b * Kk + tid];
    }
    __syncthreads();
    if (tid == 0) {
        float mx = sc[0];
        for (int k = 1; k < 10; ++k) mx = fmaxf(mx, sc[k]);
        float sm = 0.f;
        for (int k = 0; k < 10; ++k) { sc[k] = __expf(sc[k] - mx); sm += sc[k]; }
        for (int k = 0; k < 10; ++k) sc[k] /= sm;
    }
    __syncthreads();
    if (tid < 32) {
        float c = 0.f;
        for (int k = 0; k < 10; ++k) c += sc[k] * lab[k][tid];
        xS[tid] = c;                      // xt = ctx
        hS[tid] = lab[10][tid];           // h = unlabel
    }
    __syncthreads();

    for (int t = 0; t < STEPS; ++t) {
        float outp = 0.f;
        if (tid < 32) {
            int j = tid;
            float gi_r = bih[j], gi_z = bih[32 + j], gi_n = bih[64 + j];
            float gh_r = bhh[j], gh_z = bhh[32 + j], gh_n = bhh[64 + j];
#pragma unroll
            for (int i = 0; i < 32; ++i) {
                float xv = xS[i], hv = hS[i];
                gi_r += xv * Wih[i * 96 + j];
                gi_z += xv * Wih[i * 96 + 32 + j];
                gi_n += xv * Wih[i * 96 + 64 + j];
                gh_r += hv * Whh[i * 96 + j];
                gh_z += hv * Whh[i * 96 + 32 + j];
                gh_n += hv * Whh[i * 96 + 64 + j];
            }
            float r = 1.f / (1.f + __expf(-(gi_r + gh_r)));
            float z = 1.f / (1.f + __expf(-(gi_z + gh_z)));
            float n = tanhf(gi_n + r * gh_n);
            float hnew = (1.f - z) * n + z * hS[j];
            h2S[j] = hnew;
            outp = hnew * out_W[j];
        }
#pragma unroll
        for (int mm = 16; mm >= 1; mm >>= 1) outp += __shfl_xor(outp, mm);
        if (tid == 0) out[b * STEPS + t] = outp + out_b[0];
        __syncthreads();
        if (tid < 32) { hS[tid] = h2S[tid]; xS[tid] = h2S[tid]; }
        __syncthreads();
    }
}

// ---------------- launcher ----------------
extern "C" void kernel_launch(void* const* d_in, const int* in_sizes, int n_in,
                              void* d_out, int out_size, void* d_ws, size_t ws_size,
                              hipStream_t stream) {
    const float* feat    = (const float*)d_in[0];
    const float* adj     = (const float*)d_in[1];
    const float* dis_lab = (const float*)d_in[2];
    const float* W_gat   = (const float*)d_in[3];
    const float* a_gat   = (const float*)d_in[4];
    const float* qkv_W   = (const float*)d_in[5];
    const float* qkv_b   = (const float*)d_in[6];
    const float* o_W     = (const float*)d_in[7];
    const float* o_b     = (const float*)d_in[8];
    const float* fus_W   = (const float*)d_in[9];
    const float* fus_b   = (const float*)d_in[10];
    const float* att1_W  = (const float*)d_in[11];
    const float* att1_b  = (const float*)d_in[12];
    const float* att2_W  = (const float*)d_in[13];
    const float* att2_b  = (const float*)d_in[14];
    const float* Wih     = (const float*)d_in[15];
    const float* Whh     = (const float*)d_in[16];
    const float* bih     = (const float*)d_in[17];
    const float* bhh     = (const float*)d_in[18];
    const float* out_W   = (const float*)d_in[19];
    const float* out_b   = (const float*)d_in[20];
    float* out = (float*)d_out;

    float* ws = (float*)d_ws;
    // layout (floats):
    //   hid  @ 0            (921600)   live: B..D
    //   qkv  @ 921600       (2764800)  live: C..D   (overlaps dead Wh/f/g/gmax)
    //   Wh   @ 921600       (921600)   live: A..B
    //   f    @ 1843200      (28800)    live: A..B
    //   g    @ 1872000      (28800)    live: A..B
    //   gmax @ 1900800      (24)       live: A2..B
    //   hfg  @ 3686400      (8448)     live: D..E
    float* hid  = ws;
    float* qkv  = ws + 921600;
    float* Wh   = ws + 921600;
    float* fvec = ws + 1843200;
    float* gvec = ws + 1872000;
    float* Gmax = ws + 1900800;
    float* hfg  = ws + 3686400;

    gat_wh_k<<<dim3(Bb * Vv * 150), dim3(256), 0, stream>>>(feat, W_gat, a_gat, Wh, fvec, gvec);
    gmax_k<<<dim3(Bb * Vv), dim3(256), 0, stream>>>(gvec, Gmax);
    gat_attn_k<<<dim3(ROWS), dim3(64), 0, stream>>>(adj, Wh, fvec, gvec, Gmax, hid);
    qkv_k<<<dim3(ROWS * 96 / 256), dim3(256), 0, stream>>>(hid, qkv_W, qkv_b, qkv);
    attn_k<<<dim3(Bb * 33), dim3(256), 0, stream>>>(hid, qkv, o_W, o_b, fus_W, fus_b, hfg);
    head_k<<<dim3(Bb), dim3(64), 0, stream>>>(hfg, dis_lab, att1_W, att1_b, att2_W, att2_b,
                                              Wih, Whh, bih, bhh, out_W, out_b, out);
}